// Round 6
// baseline (180.482 us; speedup 1.0000x reference)
//
#include <hip/hip_runtime.h>
#include <hip/hip_bf16.h>

#define NPIX 16384   // H*W
#define NC   48      // DIM

typedef __attribute__((ext_vector_type(16))) float f32x16;
typedef __attribute__((ext_vector_type(8))) short short8v;
typedef __attribute__((ext_vector_type(8))) unsigned short ushort8v;
typedef __attribute__((ext_vector_type(2))) unsigned int uint2v;

static __device__ __forceinline__ unsigned short f2bf(float x) {
  union { float f; unsigned u; } v; v.f = x;
  unsigned r = v.u + 0x7fffu + ((v.u >> 16) & 1u);
  return (unsigned short)(r >> 16);
}

// ---------------- kernel 1: pointwise conv  out[o][p] = sum_c w[o][c]*in[c][p]
__global__ __launch_bounds__(256) void k_pointwise(const float* __restrict__ in,
                                                   const float* __restrict__ w,
                                                   float* __restrict__ out) {
  int p = blockIdx.x * 256 + threadIdx.x;
  int og = blockIdx.y * 16;
  __shared__ float wl[16][NC];
  for (int i = threadIdx.x; i < 16 * NC; i += 256)
    wl[i / NC][i % NC] = w[(og + i / NC) * NC + i % NC];
  __syncthreads();
  float acc[16];
#pragma unroll
  for (int j = 0; j < 16; ++j) acc[j] = 0.f;
  for (int c = 0; c < NC; ++c) {
    float xv = in[c * NPIX + p];
#pragma unroll
    for (int j = 0; j < 16; ++j) acc[j] += xv * wl[j][c];
  }
#pragma unroll
  for (int j = 0; j < 16; ++j) out[(og + j) * NPIX + p] = acc[j];
}

// ---------------- kernel 2: depthwise 3x3, SAME zero pad (cross-correlation)
__global__ __launch_bounds__(256) void k_dwconv(const float* __restrict__ in,
                                                const float* __restrict__ w,
                                                float* __restrict__ out) {
  int p = blockIdx.x * 256 + threadIdx.x;
  int o = blockIdx.y;
  int y = p >> 7, xx = p & 127;
  const float* base = in + o * NPIX;
  const float* wt = w + o * 9;
  float acc = 0.f;
#pragma unroll
  for (int dy = -1; dy <= 1; ++dy)
#pragma unroll
    for (int dx = -1; dx <= 1; ++dx) {
      int yy = y + dy, xc = xx + dx;
      if (yy >= 0 && yy < 128 && xc >= 0 && xc < 128)
        acc += wt[(dy + 1) * 3 + (dx + 1)] * base[yy * 128 + xc];
    }
  out[o * NPIX + p] = acc;
}

// ---------------- kernel 3: per-token l2norm of q,k -> bf16 (round-1 verified)
// qn,kn token-major [p][48]; v cast to bf16 channel-major vb[c][p]
__global__ __launch_bounds__(256) void k_norm(const float* __restrict__ dwq,
                                              const float* __restrict__ temp,
                                              unsigned short* __restrict__ qn,
                                              unsigned short* __restrict__ kn,
                                              unsigned short* __restrict__ vb) {
  int p = blockIdx.x * 256 + threadIdx.x;
  float t = temp[0];
  float qv[48], kv[48];
  float sq = 0.f, sk = 0.f;
#pragma unroll
  for (int c = 0; c < 48; ++c) {
    qv[c] = dwq[c * NPIX + p];
    kv[c] = dwq[(48 + c) * NPIX + p];
    sq += qv[c] * qv[c];
    sk += kv[c] * kv[c];
  }
  float rq = t / fmaxf(sqrtf(sq), 1e-12f);
  float rk = 1.f / fmaxf(sqrtf(sk), 1e-12f);
  unsigned short qb[48], kb[48];
#pragma unroll
  for (int c = 0; c < 48; ++c) {
    qb[c] = f2bf(qv[c] * rq);
    kb[c] = f2bf(kv[c] * rk);
  }
#pragma unroll
  for (int j = 0; j < 6; ++j) {
    *(ushort8v*)(qn + p * 48 + j * 8) = *(ushort8v*)&qb[j * 8];
    *(ushort8v*)(kn + p * 48 + j * 8) = *(ushort8v*)&kb[j * 8];
  }
#pragma unroll
  for (int c = 0; c < 48; ++c)
    vb[c * NPIX + p] = f2bf(dwq[(96 + c) * NPIX + p]);
}

// ---------------- kernel 4: MFMA attention (round-1 structure + T14 prefetch)
// grid (128 q-blocks, 4 key-splits), 256 thr = 4 waves, each wave owns one
// 32-q chunk and iterates ALL 32 key-tiles (no wave specialization).
// Per tile: issue next tile's 6 global loads into regs -> compute current
// tile -> barrier -> ds_write regs into other LDS buffer -> barrier.
// S' = mfma(K, Q) -> lane-local softmax (|S|<=t, no max, __expf), P repacked
// via cvt_pk_bf16 + permlane32_swap; O = mfma(P, V) with ones-channel = den.
// num layout: [4][49][16384] channel-major, c=48 is the denominator row.
__global__ __launch_bounds__(256) void k_attn(const unsigned short* __restrict__ qn,
                                              const unsigned short* __restrict__ kn,
                                              const unsigned short* __restrict__ vb,
                                              float* __restrict__ num) {
  __shared__ __align__(16) char smem[57344];  // 2 x (K 12288 B + Vt 16384 B)
  const int tid = threadIdx.x;
  const int lane = tid & 63, wid = tid >> 6;
  const int l31 = lane & 31, lh = lane >> 5;
  const int qb = blockIdx.x, ks = blockIdx.y;
  const int qbase = qb * 128 + wid * 32;

  // Q fragments (B operand): lane holds q-row qbase+l31, channels s*16+lh*8..+8
  short8v qf[3];
#pragma unroll
  for (int s = 0; s < 3; ++s)
    qf[s] = *(const short8v*)(qn + (qbase + l31) * 48 + s * 16 + lh * 8);

  f32x16 acc[2][2];  // [key-half h][c-block]; 4 independent MFMA chains
#pragma unroll
  for (int a = 0; a < 2; ++a)
#pragma unroll
    for (int b = 0; b < 2; ++b)
#pragma unroll
      for (int r = 0; r < 16; ++r) acc[a][b][r] = 0.f;

  // Vt pad rows 48..63 for BOTH buffers: row 48 = ones (den), rest zero.
  for (int i = tid; i < 512; i += 256) {
    int b = i >> 8, j = i & 255;
    int c = 48 + (j >> 4), kp = j & 15;
    unsigned short val = (c == 48) ? (unsigned short)0x3F80 : (unsigned short)0;
    ushort8v vv = {val, val, val, val, val, val, val, val};
    *(ushort8v*)(smem + b * 28672 + 12288 + ((c * 256 + kp * 16) ^ ((c & 7) << 4))) = vv;
  }
  // prologue: stage tile 0 into buffer 0 directly (all 256 threads, 6 chunks)
  {
    const int m0 = ks * 4096;
#pragma unroll
    for (int i = 0; i < 6; ++i) {
      int chunk = tid + 256 * i;  // 0..1535: 768 K-chunks then 768 V-chunks
      if (chunk < 768) {
        int key = chunk / 6, part = chunk - key * 6;
        short8v kv = *(const short8v*)(kn + (m0 + key) * 48 + part * 8);
        *(short8v*)(smem + ((key * 96 + part * 16) ^ ((key & 7) << 4))) = kv;
      } else {
        int c2 = (chunk - 768) >> 4, kp = (chunk - 768) & 15;
        short8v vv = *(const short8v*)(vb + c2 * NPIX + m0 + kp * 8);
        *(short8v*)(smem + 12288 + ((c2 * 256 + kp * 16) ^ ((c2 & 7) << 4))) = vv;
      }
    }
  }
  __syncthreads();

  for (int t = 0; t < 32; ++t) {
    char* buf = smem + (t & 1) * 28672;
    // ---- T14 issue-early: global loads for tile t+1 into registers ----
    short8v pf[6];
    const bool hasNext = (t + 1 < 32);
    if (hasNext) {
      const int m0n = ks * 4096 + (t + 1) * 128;
#pragma unroll
      for (int i = 0; i < 6; ++i) {
        int chunk = tid + 256 * i;
        if (chunk < 768) {
          int key = chunk / 6, part = chunk - key * 6;
          pf[i] = *(const short8v*)(kn + (m0n + key) * 48 + part * 8);
        } else {
          int c2 = (chunk - 768) >> 4, kp = (chunk - 768) & 15;
          pf[i] = *(const short8v*)(vb + c2 * NPIX + m0n + kp * 8);
        }
      }
    }
    // ---- compute tile t from buf (round-1 verified core) ----
#pragma unroll
    for (int kb = 0; kb < 128; kb += 32) {
      f32x16 sacc;
#pragma unroll
      for (int r = 0; r < 16; ++r) sacc[r] = 0.f;
      int key = kb + l31;
#pragma unroll
      for (int s = 0; s < 3; ++s) {
        short8v kf = *(const short8v*)(buf +
            ((key * 96 + s * 32 + lh * 16) ^ ((key & 7) << 4)));
        sacc = __builtin_amdgcn_mfma_f32_32x32x16_bf16(kf, qf[s], sacc, 0, 0, 0);
      }
      float p[16];
#pragma unroll
      for (int r = 0; r < 16; ++r) p[r] = __expf(sacc[r]);
#pragma unroll
      for (int h = 0; h < 2; ++h) {
        unsigned a0, a1, b0, b1;
        asm("v_cvt_pk_bf16_f32 %0, %1, %2" : "=v"(a0) : "v"(p[8 * h + 0]), "v"(p[8 * h + 1]));
        asm("v_cvt_pk_bf16_f32 %0, %1, %2" : "=v"(a1) : "v"(p[8 * h + 2]), "v"(p[8 * h + 3]));
        asm("v_cvt_pk_bf16_f32 %0, %1, %2" : "=v"(b0) : "v"(p[8 * h + 4]), "v"(p[8 * h + 5]));
        asm("v_cvt_pk_bf16_f32 %0, %1, %2" : "=v"(b1) : "v"(p[8 * h + 6]), "v"(p[8 * h + 7]));
        uint2v s0 = __builtin_amdgcn_permlane32_swap(a0, b0, false, false);
        uint2v s1 = __builtin_amdgcn_permlane32_swap(a1, b1, false, false);
        union { unsigned u[4]; short8v v; } pa;
        pa.u[0] = s0[0]; pa.u[1] = s1[0]; pa.u[2] = s0[1]; pa.u[3] = s1[1];
        int kbase = kb + 16 * h + 8 * lh;
        short8v vf0 = *(const short8v*)(buf + 12288 +
            ((l31 * 256 + kbase * 2) ^ ((l31 & 7) << 4)));
        acc[h][0] = __builtin_amdgcn_mfma_f32_32x32x16_bf16(pa.v, vf0, acc[h][0], 0, 0, 0);
        int c1 = 32 + l31;
        short8v vf1 = *(const short8v*)(buf + 12288 +
            ((c1 * 256 + kbase * 2) ^ ((c1 & 7) << 4)));
        acc[h][1] = __builtin_amdgcn_mfma_f32_32x32x16_bf16(pa.v, vf1, acc[h][1], 0, 0, 0);
      }
    }
    __syncthreads();
    // ---- T14 write-late: park prefetched tile t+1 into the other buffer ----
    if (hasNext) {
      char* sb = smem + ((t + 1) & 1) * 28672;
#pragma unroll
      for (int i = 0; i < 6; ++i) {
        int chunk = tid + 256 * i;
        if (chunk < 768) {
          int key = chunk / 6, part = chunk - key * 6;
          *(short8v*)(sb + ((key * 96 + part * 16) ^ ((key & 7) << 4))) = pf[i];
        } else {
          int c2 = (chunk - 768) >> 4, kp = (chunk - 768) & 15;
          *(short8v*)(sb + 12288 + ((c2 * 256 + kp * 16) ^ ((c2 & 7) << 4))) = pf[i];
        }
      }
    }
    __syncthreads();
  }

  // ---- epilogue (round-1 verified): merge acc halves in-register, then
  // transpose O through LDS (per-wave [32 q][52 c] region), coalesced store
  f32x16 o0, o1;
#pragma unroll
  for (int r = 0; r < 16; ++r) {
    o0[r] = acc[0][0][r] + acc[1][0][r];
    o1[r] = acc[0][1][r] + acc[1][1][r];
  }
  __syncthreads();
  float* ot = (float*)smem + wid * (32 * 52);
#pragma unroll
  for (int r = 0; r < 16; ++r) {
    int q = (r & 3) + 8 * (r >> 2) + 4 * lh;
    ot[q * 52 + l31] = o0[r];
    if (l31 < 17) ot[q * 52 + 32 + l31] = o1[r];
  }
  __syncthreads();
  for (int idx = lane; idx < 49 * 32; idx += 64) {
    int q = idx & 31, c = idx >> 5;
    num[((ks * 49 + c) << 14) + qbase + q] = ot[q * 52 + c];
  }
}

// ---------------- kernel 5: combine key-splits, divide, and project -> d_out
__global__ __launch_bounds__(256) void k_projcomb(const float* __restrict__ num,
                                                  const float* __restrict__ w,
                                                  float* __restrict__ out) {
  int p = blockIdx.x * 256 + threadIdx.x;
  __shared__ float wl[48][48];
  for (int i = threadIdx.x; i < 48 * 48; i += 256) wl[i / 48][i % 48] = w[i];
  __syncthreads();
  float d = 0.f;
#pragma unroll
  for (int ks = 0; ks < 4; ++ks) d += num[(ks * 49 + 48) * NPIX + p];
  float rd = 1.f / d;
  float tok[48];
#pragma unroll
  for (int c = 0; c < 48; ++c) {
    float s = 0.f;
#pragma unroll
    for (int ks = 0; ks < 4; ++ks) s += num[(ks * 49 + c) * NPIX + p];
    tok[c] = s * rd;
  }
  for (int o = 0; o < 48; ++o) {
    float a = 0.f;
#pragma unroll
    for (int c = 0; c < 48; ++c) a += wl[o][c] * tok[c];
    out[o * NPIX + p] = a;
  }
}

extern "C" void kernel_launch(void* const* d_in, const int* in_sizes, int n_in,
                              void* d_out, int out_size, void* d_ws, size_t ws_size,
                              hipStream_t stream) {
  const float* x      = (const float*)d_in[0];
  const float* qkv_w  = (const float*)d_in[1];
  const float* dw_w   = (const float*)d_in[2];
  const float* proj_w = (const float*)d_in[3];
  const float* temp   = (const float*)d_in[4];
  float* ws = (float*)d_ws;

  // workspace (floats), peak 18.9 MB (dwconv phase):
  //   qkv  [144][16384] @ 0          (dead after dwconv)
  //   dwq  [144][16384] @ 2359296    (dead after norm)
  //   qn/kn bf16 [16384][48] @ 0 / 393216   (overlay dead qkv)
  //   vb   bf16 [48][16384] @ 786432
  //   num  [4][49][16384] @ 1179648  (overlays dead qkv tail + dwq)
  float* qkv = ws;
  float* dwq = ws + 2359296;
  unsigned short* qn = (unsigned short*)ws;
  unsigned short* kn = (unsigned short*)(ws + 393216);
  unsigned short* vb = (unsigned short*)(ws + 786432);
  float* num  = ws + 1179648;

  k_pointwise<<<dim3(64, 9), 256, 0, stream>>>(x, qkv_w, qkv);
  k_dwconv<<<dim3(64, 144), 256, 0, stream>>>(qkv, dw_w, dwq);
  k_norm<<<dim3(64, 1), 256, 0, stream>>>(dwq, temp, qn, kn, vb);
  k_attn<<<dim3(128, 4), 256, 0, stream>>>(qn, kn, vb, num);
  k_projcomb<<<dim3(64, 1), 256, 0, stream>>>(num, proj_w, (float*)d_out);
}

// Round 7
// 149.172 us; speedup vs baseline: 1.2099x; 1.2099x over previous
//
#include <hip/hip_runtime.h>
#include <hip/hip_bf16.h>

#define NPIX 16384   // H*W
#define NC   48      // DIM

typedef __attribute__((ext_vector_type(16))) float f32x16;
typedef __attribute__((ext_vector_type(8))) short short8v;
typedef __attribute__((ext_vector_type(8))) unsigned short ushort8v;
typedef __attribute__((ext_vector_type(2))) unsigned int uint2v;

static __device__ __forceinline__ unsigned short f2bf(float x) {
  union { float f; unsigned u; } v; v.f = x;
  unsigned r = v.u + 0x7fffu + ((v.u >> 16) & 1u);
  return (unsigned short)(r >> 16);
}

// ---------------- kernel 1: pointwise conv  out[o][p] = sum_c w[o][c]*in[c][p]
__global__ __launch_bounds__(256) void k_pointwise(const float* __restrict__ in,
                                                   const float* __restrict__ w,
                                                   float* __restrict__ out) {
  int p = blockIdx.x * 256 + threadIdx.x;
  int og = blockIdx.y * 16;
  __shared__ float wl[16][NC];
  for (int i = threadIdx.x; i < 16 * NC; i += 256)
    wl[i / NC][i % NC] = w[(og + i / NC) * NC + i % NC];
  __syncthreads();
  float acc[16];
#pragma unroll
  for (int j = 0; j < 16; ++j) acc[j] = 0.f;
  for (int c = 0; c < NC; ++c) {
    float xv = in[c * NPIX + p];
#pragma unroll
    for (int j = 0; j < 16; ++j) acc[j] += xv * wl[j][c];
  }
#pragma unroll
  for (int j = 0; j < 16; ++j) out[(og + j) * NPIX + p] = acc[j];
}

// ---------------- kernel 2: depthwise 3x3, SAME zero pad (cross-correlation)
__global__ __launch_bounds__(256) void k_dwconv(const float* __restrict__ in,
                                                const float* __restrict__ w,
                                                float* __restrict__ out) {
  int p = blockIdx.x * 256 + threadIdx.x;
  int o = blockIdx.y;
  int y = p >> 7, xx = p & 127;
  const float* base = in + o * NPIX;
  const float* wt = w + o * 9;
  float acc = 0.f;
#pragma unroll
  for (int dy = -1; dy <= 1; ++dy)
#pragma unroll
    for (int dx = -1; dx <= 1; ++dx) {
      int yy = y + dy, xc = xx + dx;
      if (yy >= 0 && yy < 128 && xc >= 0 && xc < 128)
        acc += wt[(dy + 1) * 3 + (dx + 1)] * base[yy * 128 + xc];
    }
  out[o * NPIX + p] = acc;
}

// ---------------- kernel 3: per-token l2norm of q,k -> bf16.
// q additionally scaled by t*log2(e) so attn softmax uses native exp2.
// qn,kn token-major [p][48]; v cast to bf16 channel-major vb[c][p]
__global__ __launch_bounds__(64) void k_norm(const float* __restrict__ dwq,
                                             const float* __restrict__ temp,
                                             unsigned short* __restrict__ qn,
                                             unsigned short* __restrict__ kn,
                                             unsigned short* __restrict__ vb) {
  int p = blockIdx.x * 64 + threadIdx.x;
  float t = temp[0] * 1.44269504088896f;  // fold log2(e) into temperature
  float qv[48], kv[48];
  float sq = 0.f, sk = 0.f;
#pragma unroll
  for (int c = 0; c < 48; ++c) {
    qv[c] = dwq[c * NPIX + p];
    kv[c] = dwq[(48 + c) * NPIX + p];
    sq += qv[c] * qv[c];
    sk += kv[c] * kv[c];
  }
  float rq = t / fmaxf(sqrtf(sq), 1e-12f);
  float rk = 1.f / fmaxf(sqrtf(sk), 1e-12f);
  unsigned short qb[48], kb[48];
#pragma unroll
  for (int c = 0; c < 48; ++c) {
    qb[c] = f2bf(qv[c] * rq);
    kb[c] = f2bf(kv[c] * rk);
  }
#pragma unroll
  for (int j = 0; j < 6; ++j) {
    *(ushort8v*)(qn + p * 48 + j * 8) = *(ushort8v*)&qb[j * 8];
    *(ushort8v*)(kn + p * 48 + j * 8) = *(ushort8v*)&kb[j * 8];
  }
#pragma unroll
  for (int c = 0; c < 48; ++c)
    vb[c * NPIX + p] = f2bf(dwq[(96 + c) * NPIX + p]);
}

// ---------------- kernel 4: MFMA attention (round-5 verified structure)
// 1D grid 512 blocks, XCD-decoded: xcd=b&7 -> ks=xcd&3, qb=(xcd>>2)*64+(b>>3)
// so each XCD's resident blocks share one key-split (K/V 3.1 MB fits 4 MB L2).
// 256 thr = 4 waves, each wave owns one 32-q chunk, iterates all 32 key-tiles.
// Per tile: T14 issue-early global loads -> compute current -> barrier ->
// ds_write prefetch into other buffer -> barrier.
// S' = mfma(K, Q) -> lane-local softmax (|S'|<=t*log2e, no max, exp2),
// P repacked via cvt_pk_bf16 + permlane32_swap; O = mfma(P, V), ones-ch = den.
// num layout: [4][49][16384] channel-major, c=48 is the denominator row.
__global__ __launch_bounds__(256) void k_attn(const unsigned short* __restrict__ qn,
                                              const unsigned short* __restrict__ kn,
                                              const unsigned short* __restrict__ vb,
                                              float* __restrict__ num) {
  __shared__ __align__(16) char smem[57344];  // 2 x (K 12288 B + Vt 16384 B)
  const int tid = threadIdx.x;
  const int lane = tid & 63, wid = tid >> 6;
  const int l31 = lane & 31, lh = lane >> 5;
  const int bidx = blockIdx.x;
  const int xcd = bidx & 7;
  const int ks = xcd & 3;
  const int qb = (xcd >> 2) * 64 + (bidx >> 3);
  const int qbase = qb * 128 + wid * 32;

  // Q fragments (B operand): lane holds q-row qbase+l31, channels s*16+lh*8..+8
  short8v qf[3];
#pragma unroll
  for (int s = 0; s < 3; ++s)
    qf[s] = *(const short8v*)(qn + (qbase + l31) * 48 + s * 16 + lh * 8);

  f32x16 acc[2][2];  // [key-half h][c-block]; 4 independent MFMA chains
#pragma unroll
  for (int a = 0; a < 2; ++a)
#pragma unroll
    for (int b = 0; b < 2; ++b)
#pragma unroll
      for (int r = 0; r < 16; ++r) acc[a][b][r] = 0.f;

  // Vt pad rows 48..63 for BOTH buffers: row 48 = ones (den), rest zero.
  for (int i = tid; i < 512; i += 256) {
    int b = i >> 8, j = i & 255;
    int c = 48 + (j >> 4), kp = j & 15;
    unsigned short val = (c == 48) ? (unsigned short)0x3F80 : (unsigned short)0;
    ushort8v vv = {val, val, val, val, val, val, val, val};
    *(ushort8v*)(smem + b * 28672 + 12288 + ((c * 256 + kp * 16) ^ ((c & 7) << 4))) = vv;
  }
  // prologue: stage tile 0 into buffer 0 directly (all 256 threads, 6 chunks)
  {
    const int m0 = ks * 4096;
#pragma unroll
    for (int i = 0; i < 6; ++i) {
      int chunk = tid + 256 * i;  // 0..1535: 768 K-chunks then 768 V-chunks
      if (chunk < 768) {
        int key = chunk / 6, part = chunk - key * 6;
        short8v kv = *(const short8v*)(kn + (m0 + key) * 48 + part * 8);
        *(short8v*)(smem + ((key * 96 + part * 16) ^ ((key & 7) << 4))) = kv;
      } else {
        int c2 = (chunk - 768) >> 4, kp = (chunk - 768) & 15;
        short8v vv = *(const short8v*)(vb + c2 * NPIX + m0 + kp * 8);
        *(short8v*)(smem + 12288 + ((c2 * 256 + kp * 16) ^ ((c2 & 7) << 4))) = vv;
      }
    }
  }
  __syncthreads();

  for (int t = 0; t < 32; ++t) {
    char* buf = smem + (t & 1) * 28672;
    // ---- T14 issue-early: global loads for tile t+1 into registers ----
    short8v pf[6];
    const bool hasNext = (t + 1 < 32);
    if (hasNext) {
      const int m0n = ks * 4096 + (t + 1) * 128;
#pragma unroll
      for (int i = 0; i < 6; ++i) {
        int chunk = tid + 256 * i;
        if (chunk < 768) {
          int key = chunk / 6, part = chunk - key * 6;
          pf[i] = *(const short8v*)(kn + (m0n + key) * 48 + part * 8);
        } else {
          int c2 = (chunk - 768) >> 4, kp = (chunk - 768) & 15;
          pf[i] = *(const short8v*)(vb + c2 * NPIX + m0n + kp * 8);
        }
      }
    }
    // ---- compute tile t from buf ----
#pragma unroll
    for (int kb = 0; kb < 128; kb += 32) {
      f32x16 sacc;
#pragma unroll
      for (int r = 0; r < 16; ++r) sacc[r] = 0.f;
      int key = kb + l31;
#pragma unroll
      for (int s = 0; s < 3; ++s) {
        short8v kf = *(const short8v*)(buf +
            ((key * 96 + s * 32 + lh * 16) ^ ((key & 7) << 4)));
        sacc = __builtin_amdgcn_mfma_f32_32x32x16_bf16(kf, qf[s], sacc, 0, 0, 0);
      }
      float p[16];
#pragma unroll
      for (int r = 0; r < 16; ++r) p[r] = __builtin_amdgcn_exp2f(sacc[r]);
#pragma unroll
      for (int h = 0; h < 2; ++h) {
        unsigned a0, a1, b0, b1;
        asm("v_cvt_pk_bf16_f32 %0, %1, %2" : "=v"(a0) : "v"(p[8 * h + 0]), "v"(p[8 * h + 1]));
        asm("v_cvt_pk_bf16_f32 %0, %1, %2" : "=v"(a1) : "v"(p[8 * h + 2]), "v"(p[8 * h + 3]));
        asm("v_cvt_pk_bf16_f32 %0, %1, %2" : "=v"(b0) : "v"(p[8 * h + 4]), "v"(p[8 * h + 5]));
        asm("v_cvt_pk_bf16_f32 %0, %1, %2" : "=v"(b1) : "v"(p[8 * h + 6]), "v"(p[8 * h + 7]));
        uint2v s0 = __builtin_amdgcn_permlane32_swap(a0, b0, false, false);
        uint2v s1 = __builtin_amdgcn_permlane32_swap(a1, b1, false, false);
        union { unsigned u[4]; short8v v; } pa;
        pa.u[0] = s0[0]; pa.u[1] = s1[0]; pa.u[2] = s0[1]; pa.u[3] = s1[1];
        int kbase = kb + 16 * h + 8 * lh;
        short8v vf0 = *(const short8v*)(buf + 12288 +
            ((l31 * 256 + kbase * 2) ^ ((l31 & 7) << 4)));
        acc[h][0] = __builtin_amdgcn_mfma_f32_32x32x16_bf16(pa.v, vf0, acc[h][0], 0, 0, 0);
        int c1 = 32 + l31;
        short8v vf1 = *(const short8v*)(buf + 12288 +
            ((c1 * 256 + kbase * 2) ^ ((c1 & 7) << 4)));
        acc[h][1] = __builtin_amdgcn_mfma_f32_32x32x16_bf16(pa.v, vf1, acc[h][1], 0, 0, 0);
      }
    }
    __syncthreads();
    // ---- T14 write-late: park prefetched tile t+1 into the other buffer ----
    if (hasNext) {
      char* sb = smem + ((t + 1) & 1) * 28672;
#pragma unroll
      for (int i = 0; i < 6; ++i) {
        int chunk = tid + 256 * i;
        if (chunk < 768) {
          int key = chunk / 6, part = chunk - key * 6;
          *(short8v*)(sb + ((key * 96 + part * 16) ^ ((key & 7) << 4))) = pf[i];
        } else {
          int c2 = (chunk - 768) >> 4, kp = (chunk - 768) & 15;
          *(short8v*)(sb + 12288 + ((c2 * 256 + kp * 16) ^ ((c2 & 7) << 4))) = pf[i];
        }
      }
    }
    __syncthreads();
  }

  // ---- epilogue: merge acc halves in-register, then transpose O through LDS
  f32x16 o0, o1;
#pragma unroll
  for (int r = 0; r < 16; ++r) {
    o0[r] = acc[0][0][r] + acc[1][0][r];
    o1[r] = acc[0][1][r] + acc[1][1][r];
  }
  __syncthreads();
  float* ot = (float*)smem + wid * (32 * 52);
#pragma unroll
  for (int r = 0; r < 16; ++r) {
    int q = (r & 3) + 8 * (r >> 2) + 4 * lh;
    ot[q * 52 + l31] = o0[r];
    if (l31 < 17) ot[q * 52 + 32 + l31] = o1[r];
  }
  __syncthreads();
  for (int idx = lane; idx < 49 * 32; idx += 64) {
    int q = idx & 31, c = idx >> 5;
    num[((ks * 49 + c) << 14) + qbase + q] = ot[q * 52 + c];
  }
}

// ---------------- kernel 5: combine key-splits and divide -> tokT [c][p]
__global__ __launch_bounds__(256) void k_combine(const float* __restrict__ num,
                                                 float* __restrict__ tokT) {
  int p = blockIdx.x * 256 + threadIdx.x;
  int c = blockIdx.y;
  float d = 0.f, s = 0.f;
#pragma unroll
  for (int ks = 0; ks < 4; ++ks) {
    d += num[(ks * 49 + 48) * NPIX + p];
    s += num[(ks * 49 + c) * NPIX + p];
  }
  tokT[c * NPIX + p] = s / d;
}

extern "C" void kernel_launch(void* const* d_in, const int* in_sizes, int n_in,
                              void* d_out, int out_size, void* d_ws, size_t ws_size,
                              hipStream_t stream) {
  const float* x      = (const float*)d_in[0];
  const float* qkv_w  = (const float*)d_in[1];
  const float* dw_w   = (const float*)d_in[2];
  const float* proj_w = (const float*)d_in[3];
  const float* temp   = (const float*)d_in[4];
  float* ws = (float*)d_ws;

  // workspace (floats), peak 20.7 MB:
  //   qkv  [144][16384] @ 0          (dead after dwconv)
  //   dwq  [144][16384] @ 2359296    (dead after norm)
  //   qn/kn bf16 [16384][48] @ 0 / 393216   (overlay dead qkv)
  //   vb   bf16 [48][16384] @ 786432
  //   num  [4][49][16384] @ 1179648  (overlays dead qkv tail + dwq)
  //   tokT [48][16384] @ 4390912
  float* qkv = ws;
  float* dwq = ws + 2359296;
  unsigned short* qn = (unsigned short*)ws;
  unsigned short* kn = (unsigned short*)(ws + 393216);
  unsigned short* vb = (unsigned short*)(ws + 786432);
  float* num  = ws + 1179648;
  float* tokT = ws + 4390912;

  k_pointwise<<<dim3(64, 9), 256, 0, stream>>>(x, qkv_w, qkv);
  k_dwconv<<<dim3(64, 144), 256, 0, stream>>>(qkv, dw_w, dwq);
  k_norm<<<dim3(256), 64, 0, stream>>>(dwq, temp, qn, kn, vb);
  k_attn<<<dim3(512), 256, 0, stream>>>(qn, kn, vb, num);
  k_combine<<<dim3(64, 48), 256, 0, stream>>>(num, tokT);
  k_pointwise<<<dim3(64, 3), 256, 0, stream>>>(tokT, proj_w, (float*)d_out);
}

// Round 8
// 144.706 us; speedup vs baseline: 1.2472x; 1.0309x over previous
//
#include <hip/hip_runtime.h>
#include <hip/hip_bf16.h>

#define NPIX 16384   // H*W
#define NC   48      // DIM

typedef __attribute__((ext_vector_type(16))) float f32x16;
typedef __attribute__((ext_vector_type(8))) short short8v;
typedef __attribute__((ext_vector_type(8))) unsigned short ushort8v;
typedef __attribute__((ext_vector_type(2))) unsigned int uint2v;

static __device__ __forceinline__ unsigned short f2bf(float x) {
  union { float f; unsigned u; } v; v.f = x;
  unsigned r = v.u + 0x7fffu + ((v.u >> 16) & 1u);
  return (unsigned short)(r >> 16);
}

// ---------------- kernel 1: pointwise conv  out[o][p] = sum_c w[o][c]*in[c][p]
__global__ __launch_bounds__(256) void k_pointwise(const float* __restrict__ in,
                                                   const float* __restrict__ w,
                                                   float* __restrict__ out) {
  int p = blockIdx.x * 256 + threadIdx.x;
  int og = blockIdx.y * 16;
  __shared__ float wl[16][NC];
  for (int i = threadIdx.x; i < 16 * NC; i += 256)
    wl[i / NC][i % NC] = w[(og + i / NC) * NC + i % NC];
  __syncthreads();
  float acc[16];
#pragma unroll
  for (int j = 0; j < 16; ++j) acc[j] = 0.f;
  for (int c = 0; c < NC; ++c) {
    float xv = in[c * NPIX + p];
#pragma unroll
    for (int j = 0; j < 16; ++j) acc[j] += xv * wl[j][c];
  }
#pragma unroll
  for (int j = 0; j < 16; ++j) out[(og + j) * NPIX + p] = acc[j];
}

// ---------------- kernel 2: depthwise 3x3, SAME zero pad (cross-correlation)
__global__ __launch_bounds__(256) void k_dwconv(const float* __restrict__ in,
                                                const float* __restrict__ w,
                                                float* __restrict__ out) {
  int p = blockIdx.x * 256 + threadIdx.x;
  int o = blockIdx.y;
  int y = p >> 7, xx = p & 127;
  const float* base = in + o * NPIX;
  const float* wt = w + o * 9;
  float acc = 0.f;
#pragma unroll
  for (int dy = -1; dy <= 1; ++dy)
#pragma unroll
    for (int dx = -1; dx <= 1; ++dx) {
      int yy = y + dy, xc = xx + dx;
      if (yy >= 0 && yy < 128 && xc >= 0 && xc < 128)
        acc += wt[(dy + 1) * 3 + (dx + 1)] * base[yy * 128 + xc];
    }
  out[o * NPIX + p] = acc;
}

// ---------------- kernel 3: per-token l2norm of q,k -> bf16.
// q additionally scaled by t*log2(e) so attn softmax uses native exp2.
// qn,kn token-major [p][48]; v cast to bf16 channel-major vb[c][p]
__global__ __launch_bounds__(64) void k_norm(const float* __restrict__ dwq,
                                             const float* __restrict__ temp,
                                             unsigned short* __restrict__ qn,
                                             unsigned short* __restrict__ kn,
                                             unsigned short* __restrict__ vb) {
  int p = blockIdx.x * 64 + threadIdx.x;
  float t = temp[0] * 1.44269504088896f;  // fold log2(e) into temperature
  float qv[48], kv[48];
  float sq = 0.f, sk = 0.f;
#pragma unroll
  for (int c = 0; c < 48; ++c) {
    qv[c] = dwq[c * NPIX + p];
    kv[c] = dwq[(48 + c) * NPIX + p];
    sq += qv[c] * qv[c];
    sk += kv[c] * kv[c];
  }
  float rq = t / fmaxf(sqrtf(sq), 1e-12f);
  float rk = 1.f / fmaxf(sqrtf(sk), 1e-12f);
  unsigned short qb[48], kb[48];
#pragma unroll
  for (int c = 0; c < 48; ++c) {
    qb[c] = f2bf(qv[c] * rq);
    kb[c] = f2bf(kv[c] * rk);
  }
#pragma unroll
  for (int j = 0; j < 6; ++j) {
    *(ushort8v*)(qn + p * 48 + j * 8) = *(ushort8v*)&qb[j * 8];
    *(ushort8v*)(kn + p * 48 + j * 8) = *(ushort8v*)&kb[j * 8];
  }
#pragma unroll
  for (int c = 0; c < 48; ++c)
    vb[c * NPIX + p] = f2bf(dwq[(96 + c) * NPIX + p]);
}

// ---------------- kernel 4: MFMA attention (round-6 verified core,
// SINGLE-buffer LDS for occupancy + hoistable loop-invariant LDS addresses)
// 1D grid 512 blocks, XCD-decoded: xcd=b&7 -> ks=xcd&3, qb=(xcd>>2)*64+(b>>3)
// so each XCD's resident blocks share one key-split (K/V 3.1 MB fits 4 MB L2).
// 256 thr = 4 waves, each wave owns one 32-q chunk, iterates all 32 key-tiles.
// Per tile: T14 issue-early global loads (regs) -> compute current tile ->
// barrier (reads done) -> ds_write regs into SAME buffer -> barrier.
// Sync structure identical to verified double-buffer; only target changed.
// S' = mfma(K, Q) -> lane-local softmax (|S'|<=t*log2e, no max, exp2),
// P repacked via cvt_pk_bf16 + permlane32_swap; O = mfma(P, V), ones-ch = den.
// num layout: [4][49][16384] channel-major, c=48 is the denominator row.
__global__ __launch_bounds__(256, 3) void k_attn(const unsigned short* __restrict__ qn,
                                                 const unsigned short* __restrict__ kn,
                                                 const unsigned short* __restrict__ vb,
                                                 float* __restrict__ num) {
  __shared__ __align__(16) char smem[28672];  // K 12288 B + Vt 16384 B (1 buf)
  const int tid = threadIdx.x;
  const int lane = tid & 63, wid = tid >> 6;
  const int l31 = lane & 31, lh = lane >> 5;
  const int bidx = blockIdx.x;
  const int xcd = bidx & 7;
  const int ks = xcd & 3;
  const int qb = (xcd >> 2) * 64 + (bidx >> 3);
  const int qbase = qb * 128 + wid * 32;

  // Q fragments (B operand): lane holds q-row qbase+l31, channels s*16+lh*8..+8
  short8v qf[3];
#pragma unroll
  for (int s = 0; s < 3; ++s)
    qf[s] = *(const short8v*)(qn + (qbase + l31) * 48 + s * 16 + lh * 8);

  f32x16 acc[2][2];  // [key-half h][c-block]; 4 independent MFMA chains
#pragma unroll
  for (int a = 0; a < 2; ++a)
#pragma unroll
    for (int b = 0; b < 2; ++b)
#pragma unroll
      for (int r = 0; r < 16; ++r) acc[a][b][r] = 0.f;

  // Vt pad rows 48..63: row 48 = ones (den), rest zero. Written once.
  {
    int c = 48 + (tid >> 4), kp = tid & 15;
    unsigned short val = (c == 48) ? (unsigned short)0x3F80 : (unsigned short)0;
    ushort8v vv = {val, val, val, val, val, val, val, val};
    *(ushort8v*)(smem + 12288 + ((c * 256 + kp * 16) ^ ((c & 7) << 4))) = vv;
  }
  // prologue: stage tile 0 (all 256 threads, 6 chunks)
  {
    const int m0 = ks * 4096;
#pragma unroll
    for (int i = 0; i < 6; ++i) {
      int chunk = tid + 256 * i;  // 0..1535: 768 K-chunks then 768 V-chunks
      if (chunk < 768) {
        int key = chunk / 6, part = chunk - key * 6;
        short8v kv = *(const short8v*)(kn + (m0 + key) * 48 + part * 8);
        *(short8v*)(smem + ((key * 96 + part * 16) ^ ((key & 7) << 4))) = kv;
      } else {
        int c2 = (chunk - 768) >> 4, kp = (chunk - 768) & 15;
        short8v vv = *(const short8v*)(vb + c2 * NPIX + m0 + kp * 8);
        *(short8v*)(smem + 12288 + ((c2 * 256 + kp * 16) ^ ((c2 & 7) << 4))) = vv;
      }
    }
  }
  __syncthreads();

  for (int t = 0; t < 32; ++t) {
    // ---- T14 issue-early: global loads for tile t+1 into registers ----
    short8v pf[6];
    const bool hasNext = (t + 1 < 32);
    if (hasNext) {
      const int m0n = ks * 4096 + (t + 1) * 128;
#pragma unroll
      for (int i = 0; i < 6; ++i) {
        int chunk = tid + 256 * i;
        if (chunk < 768) {
          int key = chunk / 6, part = chunk - key * 6;
          pf[i] = *(const short8v*)(kn + (m0n + key) * 48 + part * 8);
        } else {
          int c2 = (chunk - 768) >> 4, kp = (chunk - 768) & 15;
          pf[i] = *(const short8v*)(vb + c2 * NPIX + m0n + kp * 8);
        }
      }
    }
    // ---- compute tile t (all LDS read addrs loop-invariant -> hoisted) ----
#pragma unroll
    for (int kb = 0; kb < 128; kb += 32) {
      f32x16 sacc;
#pragma unroll
      for (int r = 0; r < 16; ++r) sacc[r] = 0.f;
      int key = kb + l31;
#pragma unroll
      for (int s = 0; s < 3; ++s) {
        short8v kf = *(const short8v*)(smem +
            ((key * 96 + s * 32 + lh * 16) ^ ((key & 7) << 4)));
        sacc = __builtin_amdgcn_mfma_f32_32x32x16_bf16(kf, qf[s], sacc, 0, 0, 0);
      }
      float p[16];
#pragma unroll
      for (int r = 0; r < 16; ++r) p[r] = __builtin_amdgcn_exp2f(sacc[r]);
#pragma unroll
      for (int h = 0; h < 2; ++h) {
        unsigned a0, a1, b0, b1;
        asm("v_cvt_pk_bf16_f32 %0, %1, %2" : "=v"(a0) : "v"(p[8 * h + 0]), "v"(p[8 * h + 1]));
        asm("v_cvt_pk_bf16_f32 %0, %1, %2" : "=v"(a1) : "v"(p[8 * h + 2]), "v"(p[8 * h + 3]));
        asm("v_cvt_pk_bf16_f32 %0, %1, %2" : "=v"(b0) : "v"(p[8 * h + 4]), "v"(p[8 * h + 5]));
        asm("v_cvt_pk_bf16_f32 %0, %1, %2" : "=v"(b1) : "v"(p[8 * h + 6]), "v"(p[8 * h + 7]));
        uint2v s0 = __builtin_amdgcn_permlane32_swap(a0, b0, false, false);
        uint2v s1 = __builtin_amdgcn_permlane32_swap(a1, b1, false, false);
        union { unsigned u[4]; short8v v; } pa;
        pa.u[0] = s0[0]; pa.u[1] = s1[0]; pa.u[2] = s0[1]; pa.u[3] = s1[1];
        int kbase = kb + 16 * h + 8 * lh;
        short8v vf0 = *(const short8v*)(smem + 12288 +
            ((l31 * 256 + kbase * 2) ^ ((l31 & 7) << 4)));
        acc[h][0] = __builtin_amdgcn_mfma_f32_32x32x16_bf16(pa.v, vf0, acc[h][0], 0, 0, 0);
        int c1 = 32 + l31;
        short8v vf1 = *(const short8v*)(smem + 12288 +
            ((c1 * 256 + kbase * 2) ^ ((c1 & 7) << 4)));
        acc[h][1] = __builtin_amdgcn_mfma_f32_32x32x16_bf16(pa.v, vf1, acc[h][1], 0, 0, 0);
      }
    }
    __syncthreads();  // all waves done READING tile t
    // ---- T14 write-late: park prefetched tile t+1 into the (same) buffer ----
    if (hasNext) {
#pragma unroll
      for (int i = 0; i < 6; ++i) {
        int chunk = tid + 256 * i;
        if (chunk < 768) {
          int key = chunk / 6, part = chunk - key * 6;
          *(short8v*)(smem + ((key * 96 + part * 16) ^ ((key & 7) << 4))) = pf[i];
        } else {
          int c2 = (chunk - 768) >> 4, kp = (chunk - 768) & 15;
          *(short8v*)(smem + 12288 + ((c2 * 256 + kp * 16) ^ ((c2 & 7) << 4))) = pf[i];
        }
      }
    }
    __syncthreads();  // writes visible before next compute
  }

  // ---- epilogue: merge acc halves in-register, then transpose O through LDS
  f32x16 o0, o1;
#pragma unroll
  for (int r = 0; r < 16; ++r) {
    o0[r] = acc[0][0][r] + acc[1][0][r];
    o1[r] = acc[0][1][r] + acc[1][1][r];
  }
  __syncthreads();
  float* ot = (float*)smem + wid * (32 * 52);
#pragma unroll
  for (int r = 0; r < 16; ++r) {
    int q = (r & 3) + 8 * (r >> 2) + 4 * lh;
    ot[q * 52 + l31] = o0[r];
    if (l31 < 17) ot[q * 52 + 32 + l31] = o1[r];
  }
  __syncthreads();
  for (int idx = lane; idx < 49 * 32; idx += 64) {
    int q = idx & 31, c = idx >> 5;
    num[((ks * 49 + c) << 14) + qbase + q] = ot[q * 52 + c];
  }
}

// ---------------- kernel 5: combine key-splits and divide -> tokT [c][p]
__global__ __launch_bounds__(256) void k_combine(const float* __restrict__ num,
                                                 float* __restrict__ tokT) {
  int p = blockIdx.x * 256 + threadIdx.x;
  int c = blockIdx.y;
  float d = 0.f, s = 0.f;
#pragma unroll
  for (int ks = 0; ks < 4; ++ks) {
    d += num[(ks * 49 + 48) * NPIX + p];
    s += num[(ks * 49 + c) * NPIX + p];
  }
  tokT[c * NPIX + p] = s / d;
}

extern "C" void kernel_launch(void* const* d_in, const int* in_sizes, int n_in,
                              void* d_out, int out_size, void* d_ws, size_t ws_size,
                              hipStream_t stream) {
  const float* x      = (const float*)d_in[0];
  const float* qkv_w  = (const float*)d_in[1];
  const float* dw_w   = (const float*)d_in[2];
  const float* proj_w = (const float*)d_in[3];
  const float* temp   = (const float*)d_in[4];
  float* ws = (float*)d_ws;

  // workspace (floats), peak 20.7 MB:
  //   qkv  [144][16384] @ 0          (dead after dwconv)
  //   dwq  [144][16384] @ 2359296    (dead after norm)
  //   qn/kn bf16 [16384][48] @ 0 / 393216   (overlay dead qkv)
  //   vb   bf16 [48][16384] @ 786432
  //   num  [4][49][16384] @ 1179648  (overlays dead qkv tail + dwq)
  //   tokT [48][16384] @ 4390912
  float* qkv = ws;
  float* dwq = ws + 2359296;
  unsigned short* qn = (unsigned short*)ws;
  unsigned short* kn = (unsigned short*)(ws + 393216);
  unsigned short* vb = (unsigned short*)(ws + 786432);
  float* num  = ws + 1179648;
  float* tokT = ws + 4390912;

  k_pointwise<<<dim3(64, 9), 256, 0, stream>>>(x, qkv_w, qkv);
  k_dwconv<<<dim3(64, 144), 256, 0, stream>>>(qkv, dw_w, dwq);
  k_norm<<<dim3(256), 64, 0, stream>>>(dwq, temp, qn, kn, vb);
  k_attn<<<dim3(512), 256, 0, stream>>>(qn, kn, vb, num);
  k_combine<<<dim3(64, 48), 256, 0, stream>>>(num, tokT);
  k_pointwise<<<dim3(64, 3), 256, 0, stream>>>(tokT, proj_w, (float*)d_out);
}